// Round 1
// baseline (29.159 us; speedup 1.0000x reference)
//
#include <hip/hip_runtime.h>

#define NQ 4
#define DIM 16
#define NPAIR 136   // 16*17/2

// ---------------------------------------------------------------------------
// Prep kernel (1 block): build the constant circuit unitary U (post initial-RY
// layer) column by column, then A_q = Re(U^T* Z_q U), packed upper-triangular
// with off-diagonals doubled: Apack[pair][q], pair runs (i<=j).
// ---------------------------------------------------------------------------
__global__ __launch_bounds__(256) void qnn_prep(const float* __restrict__ w,
                                                float* __restrict__ Apack) {
    __shared__ float Ure[DIM][DIM + 1];
    __shared__ float Uim[DIM][DIM + 1];
    const int tid = threadIdx.x;

    if (tid < DIM) {
        float re[DIM], im[DIM];
#pragma unroll
        for (int k = 0; k < DIM; ++k) { re[k] = (k == tid) ? 1.f : 0.f; im[k] = 0.f; }

        // Two parametrized layers with CNOT chain in between.
#pragma unroll
        for (int layer = 0; layer < 2; ++layer) {
#pragma unroll
            for (int q = 0; q < NQ; ++q) {
                const int bit = 1 << (3 - q);
                const int g = layer * NQ + q;
                // RZ(w[g][0]): diag(e^{-i t/2}, e^{+i t/2})
                float sr, cr;
                sincosf(0.5f * w[g * 2 + 0], &sr, &cr);
#pragma unroll
                for (int k = 0; k < DIM; ++k) {
                    if (!(k & bit)) {
                        const int k1 = k | bit;
                        float r0 = re[k], i0 = im[k], r1 = re[k1], i1 = im[k1];
                        re[k]  = r0 * cr + i0 * sr;  im[k]  = i0 * cr - r0 * sr;
                        re[k1] = r1 * cr - i1 * sr;  im[k1] = i1 * cr + r1 * sr;
                    }
                }
                // RY(w[g][1]): [[c,-s],[s,c]]
                float sy, cy;
                sincosf(0.5f * w[g * 2 + 1], &sy, &cy);
#pragma unroll
                for (int k = 0; k < DIM; ++k) {
                    if (!(k & bit)) {
                        const int k1 = k | bit;
                        float r0 = re[k], i0 = im[k], r1 = re[k1], i1 = im[k1];
                        re[k]  = cy * r0 - sy * r1;  im[k]  = cy * i0 - sy * i1;
                        re[k1] = sy * r0 + cy * r1;  im[k1] = sy * i0 + cy * i1;
                    }
                }
            }
            if (layer == 0) {
                // CNOT chain c=0..2: control bit (3-c), target bit (2-c)
#pragma unroll
                for (int c = 0; c < 3; ++c) {
                    const int cb = 1 << (3 - c), tb = 1 << (2 - c);
#pragma unroll
                    for (int k = 0; k < DIM; ++k) {
                        if ((k & cb) && !(k & tb)) {
                            const int k1 = k | tb;
                            float t;
                            t = re[k]; re[k] = re[k1]; re[k1] = t;
                            t = im[k]; im[k] = im[k1]; im[k1] = t;
                        }
                    }
                }
            }
        }
#pragma unroll
        for (int k = 0; k < DIM; ++k) { Ure[k][tid] = re[k]; Uim[k][tid] = im[k]; }
    }
    __syncthreads();

    if (tid < NPAIR) {
        // decode pair index -> (i, j) with i <= j
        int i = 0, j = 0, pp = tid;
        for (i = 0; i < DIM; ++i) {
            const int row = DIM - i;
            if (pp < row) { j = i + pp; break; }
            pp -= row;
        }
        const float f = (i == j) ? 1.f : 2.f;
#pragma unroll
        for (int q = 0; q < NQ; ++q) {
            float acc = 0.f;
#pragma unroll
            for (int k = 0; k < DIM; ++k) {
                const float zq = ((k >> (3 - q)) & 1) ? -1.f : 1.f;
                acc += zq * (Ure[k][i] * Ure[k][j] + Uim[k][i] * Uim[k][j]);
            }
            Apack[tid * 4 + q] = f * acc;
        }
    }
}

// ---------------------------------------------------------------------------
// Main kernel: one batch element per thread.
// angles = x @ fm_w^T + fm_b ; s = kron of per-qubit (cos, sin) ;
// out[q] = s^T A_q s  via packed pairs.
// ---------------------------------------------------------------------------
__global__ __launch_bounds__(256) void qnn_main(const float* __restrict__ x,
                                                const float* __restrict__ fm_w,
                                                const float* __restrict__ fm_b,
                                                const float* __restrict__ Apack,
                                                float* __restrict__ out, int B) {
    const int b = blockIdx.x * 256 + threadIdx.x;
    if (b >= B) return;

    // --- angles: 4 dot products of length 64, float4-vectorized ---
    float acc[NQ];
#pragma unroll
    for (int q = 0; q < NQ; ++q) acc[q] = fm_b[q];

    const float4* __restrict__ x4 = (const float4*)(x + (size_t)b * 64);
    const float4* __restrict__ w4 = (const float4*)fm_w;
#pragma unroll
    for (int t = 0; t < 16; ++t) {
        const float4 xv = x4[t];
#pragma unroll
        for (int q = 0; q < NQ; ++q) {
            const float4 wv = w4[q * 16 + t];  // uniform -> scalar loads
            acc[q] += xv.x * wv.x + xv.y * wv.y + xv.z * wv.z + xv.w * wv.w;
        }
    }

    // --- per-qubit cos/sin of a/2 ---
    float c[NQ], s[NQ];
#pragma unroll
    for (int q = 0; q < NQ; ++q) __sincosf(0.5f * acc[q], &s[q], &c[q]);

    // --- product state via Kronecker tree (qubit 0 = MSB of index) ---
    float p01[4], p23[4];
#pragma unroll
    for (int u = 0; u < 4; ++u) {
        p01[u] = ((u & 2) ? s[0] : c[0]) * ((u & 1) ? s[1] : c[1]);
        p23[u] = ((u & 2) ? s[2] : c[2]) * ((u & 1) ? s[3] : c[3]);
    }
    float st[DIM];
#pragma unroll
    for (int i = 0; i < DIM; ++i) st[i] = p01[i >> 2] * p23[i & 3];

    // --- four quadratic forms over packed pairs ---
    float o0 = 0.f, o1 = 0.f, o2 = 0.f, o3 = 0.f;
    const float4* __restrict__ A4 = (const float4*)Apack;
    int p = 0;
#pragma unroll
    for (int i = 0; i < DIM; ++i) {
#pragma unroll
        for (int j = i; j < DIM; ++j) {
            const float pr = st[i] * st[j];
            const float4 aq = A4[p];  // uniform -> s_load_dwordx4
            o0 += aq.x * pr; o1 += aq.y * pr; o2 += aq.z * pr; o3 += aq.w * pr;
            ++p;
        }
    }

    float4 o = make_float4(o0, o1, o2, o3);
    *(float4*)(out + (size_t)b * 4) = o;
}

extern "C" void kernel_launch(void* const* d_in, const int* in_sizes, int n_in,
                              void* d_out, int out_size, void* d_ws, size_t ws_size,
                              hipStream_t stream) {
    const float* x    = (const float*)d_in[0];
    const float* fm_w = (const float*)d_in[1];
    const float* fm_b = (const float*)d_in[2];
    const float* qw   = (const float*)d_in[3];
    float* out = (float*)d_out;
    float* Apack = (float*)d_ws;  // 136*4 floats = 2176 B

    const int B = in_sizes[0] / 64;

    qnn_prep<<<1, 256, 0, stream>>>(qw, Apack);
    qnn_main<<<(B + 255) / 256, 256, 0, stream>>>(x, fm_w, fm_b, Apack, out, B);
}